// Round 2
// baseline (299.460 us; speedup 1.0000x reference)
//
#include <hip/hip_runtime.h>

#define NZ 1e-5f
#define TC 16   // timesteps per staged LDS tile
#define NB 2    // independent basins per lane (ILP source: 2 interleaved chains)

__device__ __forceinline__ float fast_exp2(float x) {
#if __has_builtin(__builtin_amdgcn_exp2f)
    return __builtin_amdgcn_exp2f(x);   // v_exp_f32
#else
    return exp2f(x);
#endif
}

__device__ __forceinline__ float fast_log2(float x) {
#if __has_builtin(__builtin_amdgcn_logf)
    return __builtin_amdgcn_logf(x);    // v_log_f32 (base-2)
#else
    return log2f(x);
#endif
}

// Async global->LDS, 16B/lane. LDS dest is wave-uniform base + lane*16;
// global source address is per-lane.
__device__ __forceinline__ void gload_lds16(const float* src, float* dst_lds) {
    __builtin_amdgcn_global_load_lds(
        (const __attribute__((address_space(1))) void*)src,
        (__attribute__((address_space(3))) void*)dst_lds,
        16, 0, 0);
}

// R1 post-mortem: async LDS staging did NOT move dur (110us vs 107us) -- the
// bottleneck is the serial HBV dependency chain at <1 wave/SIMD (zero TLP,
// ~550 stall cycles/step vs ~160 issue cycles). Fix: NB=2 independent basins
// per lane. Two independent chains give the scheduler issue work to fill the
// latency bubbles. 391 waves remain (>=1/CU, all concurrent).
__global__ __launch_bounds__(64, 1) void hbv_kernel(
    const float* __restrict__ precip,
    const float* __restrict__ temp,
    const float* __restrict__ pet,
    const float* __restrict__ phy,
    float* __restrict__ out,
    int G, int T)
{
    // [buf][array][t_sub][basin] : 2*3*16*128*4 = 49152 B
    __shared__ float lds[2][3][TC][64 * NB];

    const int lane = threadIdx.x;            // 0..63
    const int g0   = blockIdx.x * (64 * NB); // first basin of this block

    // Per-lane basin pair: g0 + 2*lane, g0 + 2*lane + 1 (adjacent -> float2 I/O)
    bool vb[NB];
    int  gb[NB];
#pragma unroll
    for (int c = 0; c < NB; ++c) {
        const int g = g0 + NB * lane + c;
        vb[c] = (g < G);
        gb[c] = vb[c] ? g : (G - 1);         // clamped (no early return: all
    }                                        // lanes must participate in staging)

    // Parameter bounds (compile-time constants, folded)
    const float lo[14] = {1.0f, 50.0f, 0.05f, 0.01f, 0.001f, 0.2f, 0.0f,
                          0.0f, -2.5f, 0.5f, 0.0f, 0.0f, 0.3f, 0.0f};
    const float hi[14] = {6.0f, 1000.0f, 0.9f, 0.5f, 0.2f, 1.0f, 10.0f,
                          100.0f, 2.5f, 10.0f, 0.1f, 0.2f, 5.0f, 1.0f};

    float P[NB][14];
#pragma unroll
    for (int c = 0; c < NB; ++c)
#pragma unroll
        for (int i = 0; i < 14; ++i)
            P[c][i] = lo[i] + phy[gb[c] * 14 + i] * (hi[i] - lo[i]);

    float invFC_[NB], invLPFC_[NB], CFRX_[NB];
#pragma unroll
    for (int c = 0; c < NB; ++c) {
        invFC_[c]   = 1.0f / P[c][1];
        invLPFC_[c] = 1.0f / (P[c][5] * P[c][1]);
        CFRX_[c]    = P[c][10] * P[c][9];
    }

    // State (registers for the whole scan), per chain
    float SP[NB], MW[NB], SM[NB], SUZ[NB], SLZ[NB];
#pragma unroll
    for (int c = 0; c < NB; ++c) {
        SP[c] = NZ; MW[c] = NZ; SM[c] = NZ; SUZ[c] = NZ; SLZ[c] = NZ;
    }

    // --- HBV step: byte-identical math to the verified passing kernel ---
    // c is always a compile-time constant (unrolled callers) -> registers.
    auto hbv_step = [&](int c, float pr, float tm, float pe) -> float {
        const float BETA = P[c][0], FC = P[c][1], K0 = P[c][2], K1 = P[c][3];
        const float K2 = P[c][4], PERCp = P[c][6], UZL = P[c][7], TT = P[c][8];
        const float CFMAX = P[c][9], CWH = P[c][11], BETAET = P[c][12], C = P[c][13];
        const float invFC = invFC_[c], invLPFC = invLPFC_[c], CFRX = CFRX_[c];

        const float RAIN = (tm >= TT) ? pr : 0.0f;
        const float SNOW = pr - RAIN;
        SP[c] += SNOW;
        float melt = fminf(fmaxf(CFMAX * (tm - TT), 0.0f), SP[c]);
        MW[c] += melt;
        SP[c] -= melt;
        float refr = fminf(fmaxf(CFRX * (TT - tm), 0.0f), MW[c]);
        SP[c] += refr;
        MW[c] -= refr;
        float tosoil = fmaxf(MW[c] - CWH * SP[c], 0.0f);
        MW[c] -= tosoil;
        float sw = fminf(fast_exp2(BETA * fast_log2(SM[c] * invFC)), 1.0f);
        float rt = RAIN + tosoil;
        float recharge = rt * sw;
        SM[c] += rt - recharge;
        float excess = fmaxf(SM[c] - FC, 0.0f);
        SM[c] -= excess;
        float ef = fminf(fast_exp2(BETAET * fast_log2(SM[c] * invLPFC)), 1.0f);
        float ETact = fminf(SM[c], pe * ef);
        SM[c] = fmaxf(SM[c] - ETact, NZ);
        float cap = fminf(SLZ[c], C * SLZ[c] * (1.0f - fminf(SM[c] * invFC, 1.0f)));
        SM[c] = fmaxf(SM[c] + cap, NZ);
        SLZ[c] = fmaxf(SLZ[c] - cap, NZ);
        SUZ[c] += recharge + excess;
        float PERC = fminf(SUZ[c], PERCp);
        SUZ[c] -= PERC;
        float Q0 = K0 * fmaxf(SUZ[c] - UZL, 0.0f);
        SUZ[c] -= Q0;
        float Q1 = K1 * SUZ[c];
        SUZ[c] -= Q1;
        SLZ[c] = fmaxf(SLZ[c] + PERC, 0.0f);
        float Q2 = K2 * SLZ[c];
        SLZ[c] -= Q2;
        return Q0 + Q1 + Q2;
    };

    if ((G & 3) == 0) {
        // ---- fast path: async LDS staging (needs 16B-aligned rows: G%4==0) ----
        const int rsub = lane >> 5;          // which row of the 2-row pair
        const int csub = (lane & 31) << 2;   // float col within the 128-basin row
        int gcol = g0 + csub;
        if (gcol > G - 4) gcol = G - 4;      // clamp (only ever hits invalid basins)

        const int nt = (T + TC - 1) / TC;
        // uniform per block: full blocks always issue exactly 16 stores/tile
        const bool full = (g0 + 64 * NB <= G);

        // One tile = 16 rows x 128 basins x 3 arrays. Each width-16 load covers
        // 2 rows (64 lanes x 16B = 1KiB): 8 instrs/array, 24 per tile.
        auto issue_tile = [&](int k, int b) {
            const int t0 = k * TC;
#pragma unroll
            for (int q = 0; q < TC / 2; ++q) {
                int t = t0 + 2 * q + rsub;
                if (t > T - 1) t = T - 1;    // tail clamp: duplicate rows, never consumed
                const size_t off = (size_t)t * G + gcol;
                gload_lds16(precip + off, &lds[b][0][2 * q][0]);
                gload_lds16(temp   + off, &lds[b][1][2 * q][0]);
                gload_lds16(pet    + off, &lds[b][2][2 * q][0]);
            }
        };

        issue_tile(0, 0);
        asm volatile("s_waitcnt vmcnt(0)" ::: "memory");
        __builtin_amdgcn_sched_barrier(0);

        for (int k = 0; k < nt; ++k) {
            const int b = k & 1;
            if (k + 1 < nt) {
                issue_tile(k + 1, b ^ 1);            // 24 loads in flight across the
                __builtin_amdgcn_sched_barrier(0);   // whole compute phase below
            }
            const int t0 = k * TC;
#pragma unroll
            for (int j = 0; j < TC; ++j) {
                const int t = t0 + j;
                // ds_read_b64 per array: lane's 2 basins at col 2*lane
                const float2 prv = *(const float2*)&lds[b][0][j][NB * lane];
                const float2 tmv = *(const float2*)&lds[b][1][j][NB * lane];
                const float2 pev = *(const float2*)&lds[b][2][j][NB * lane];
                // two independent chains -> scheduler interleaves them
                const float q0 = hbv_step(0, prv.x, tmv.x, pev.x);
                const float q1 = hbv_step(1, prv.y, tmv.y, pev.y);
                if (t < T) {
                    const size_t idx = (size_t)t * G + (g0 + NB * lane);
                    if (vb[1])
                        *(float2*)&out[idx] = make_float2(q0, q1);
                    else if (vb[0])
                        out[idx] = q0;
                }
            }
            if (k + 1 < nt) {
                if (full) {
                    // Counted wait (T4): outstanding = 24 next-tile loads (oldest)
                    // + 16 just-issued stores. vmcnt(16) retires exactly the 24
                    // loads (issued ~a full tile of compute ago -> ~zero stall)
                    // without draining the stores.
                    asm volatile("s_waitcnt vmcnt(16)" ::: "memory");
                } else {
                    // partial tail block: store count per tile is not statically
                    // 16 -> conservative drain (1 block of 391, negligible)
                    asm volatile("s_waitcnt vmcnt(0)" ::: "memory");
                }
                __builtin_amdgcn_sched_barrier(0);
            }
        }
    } else {
        // ---- generic fallback (not taken for the bench shape) ----
        for (int t = 0; t < T; ++t) {
            float q[NB];
#pragma unroll
            for (int c = 0; c < NB; ++c) {
                const size_t idx = (size_t)t * G + gb[c];
                q[c] = hbv_step(c, precip[idx], temp[idx], pet[idx]);
            }
#pragma unroll
            for (int c = 0; c < NB; ++c)
                if (vb[c]) out[(size_t)t * G + gb[c]] = q[c];
        }
    }
}

extern "C" void kernel_launch(void* const* d_in, const int* in_sizes, int n_in,
                              void* d_out, int out_size, void* d_ws, size_t ws_size,
                              hipStream_t stream) {
    const float* precip = (const float*)d_in[0];
    const float* temp   = (const float*)d_in[1];
    const float* pet    = (const float*)d_in[2];
    const float* phy    = (const float*)d_in[3];
    float* out = (float*)d_out;

    const int G = in_sizes[3] / 14;   // 50000
    const int T = in_sizes[0] / G;    // 365

    dim3 block(64);
    dim3 grid((G + 64 * NB - 1) / (64 * NB));  // 391 blocks, 1 wave each
    hbv_kernel<<<grid, block, 0, stream>>>(precip, temp, pet, phy, out, G, T);
}

// Round 3
// 253.209 us; speedup vs baseline: 1.1827x; 1.1827x over previous
//
#include <hip/hip_runtime.h>

#define NZ 1e-5f
#define TC 16   // timesteps per staged LDS tile

__device__ __forceinline__ float fast_exp2(float x) {
#if __has_builtin(__builtin_amdgcn_exp2f)
    return __builtin_amdgcn_exp2f(x);   // v_exp_f32
#else
    return exp2f(x);
#endif
}

__device__ __forceinline__ float fast_log2(float x) {
#if __has_builtin(__builtin_amdgcn_logf)
    return __builtin_amdgcn_logf(x);    // v_log_f32 (base-2)
#else
    return log2f(x);
#endif
}

// Async global->LDS, 16B/lane. LDS dest is wave-uniform base + lane*16;
// global source address is per-lane.
__device__ __forceinline__ void gload_lds16(const float* src, float* dst_lds) {
    __builtin_amdgcn_global_load_lds(
        (const __attribute__((address_space(1))) void*)src,
        (__attribute__((address_space(3))) void*)dst_lds,
        16, 0, 0);
}

// R2 post-mortem: NB=2 lost (163us) -- wall = 365 * per-wave-step-time, and the
// stall per step did not shrink (whole-wave stalls, not per-chain latency).
// R3: NB=1 (782 waves) + EXPLICIT 2-stage software pipeline per iteration:
//   { ds_reads(t+2) } || { snow(t+1): SP,MW only } || { soil(t): SM,SUZ,SLZ }
// The three streams are data-independent (snow feeds soil only via rt, skewed
// one step), so the scheduler gets off-path work to fill the soil chain's
// transcendental/dependency bubbles, and LDS reads get a full iteration of lead.
// All arithmetic is op-for-op identical to the verified kernel (absmax 0.0625).
__global__ __launch_bounds__(64, 1) void hbv_kernel(
    const float* __restrict__ precip,
    const float* __restrict__ temp,
    const float* __restrict__ pet,
    const float* __restrict__ phy,
    float* __restrict__ out,
    int G, int T)
{
    // [buf][array][t_sub][g_sub] : 2*3*16*64*4 = 24576 B
    __shared__ float lds[2][3][TC][64];

    const int lane = threadIdx.x;            // 0..63
    const int g0   = blockIdx.x * 64;
    const int g    = g0 + lane;
    const bool valid = (g < G);
    const int gp   = valid ? g : (G - 1);    // clamped (no early return: all
                                             // lanes must participate in staging)

    // Parameter bounds (compile-time constants, folded)
    const float lo[14] = {1.0f, 50.0f, 0.05f, 0.01f, 0.001f, 0.2f, 0.0f,
                          0.0f, -2.5f, 0.5f, 0.0f, 0.0f, 0.3f, 0.0f};
    const float hi[14] = {6.0f, 1000.0f, 0.9f, 0.5f, 0.2f, 1.0f, 10.0f,
                          100.0f, 2.5f, 10.0f, 0.1f, 0.2f, 5.0f, 1.0f};
    float p[14];
#pragma unroll
    for (int i = 0; i < 14; ++i)
        p[i] = lo[i] + phy[gp * 14 + i] * (hi[i] - lo[i]);

    const float BETA = p[0], FC = p[1], K0 = p[2], K1 = p[3], K2 = p[4];
    const float LP = p[5], PERCp = p[6], UZL = p[7], TT = p[8], CFMAX = p[9];
    const float CFR = p[10], CWH = p[11], BETAET = p[12], C = p[13];
    const float invFC   = 1.0f / FC;
    const float invLPFC = 1.0f / (LP * FC);
    const float CFRX    = CFR * CFMAX;
    (void)LP; (void)CFR;

    // State (registers for the whole scan)
    float SP = NZ, MW = NZ, SM = NZ, SUZ = NZ, SLZ = NZ;

    // --- snow phase: touches ONLY SP, MW. Returns rt = RAIN + tosoil. ---
    // Op-for-op identical to the verified kernel's first half.
    auto snow_phase = [&](float pr, float tm) -> float {
        const float RAIN = (tm >= TT) ? pr : 0.0f;
        const float SNOW = pr - RAIN;
        SP += SNOW;
        float melt = fminf(fmaxf(CFMAX * (tm - TT), 0.0f), SP);
        MW += melt;
        SP -= melt;
        float refr = fminf(fmaxf(CFRX * (TT - tm), 0.0f), MW);
        SP += refr;
        MW -= refr;
        float tosoil = fmaxf(MW - CWH * SP, 0.0f);
        MW -= tosoil;
        return RAIN + tosoil;
    };

    // --- soil/routing phase: touches ONLY SM, SUZ, SLZ. Consumes (rt, pe). ---
    auto soil_phase = [&](float rt, float pe) -> float {
        float sw = fminf(fast_exp2(BETA * fast_log2(SM * invFC)), 1.0f);
        float recharge = rt * sw;
        SM += rt - recharge;
        float excess = fmaxf(SM - FC, 0.0f);
        SM -= excess;
        float ef = fminf(fast_exp2(BETAET * fast_log2(SM * invLPFC)), 1.0f);
        float ETact = fminf(SM, pe * ef);
        SM = fmaxf(SM - ETact, NZ);
        float cap = fminf(SLZ, C * SLZ * (1.0f - fminf(SM * invFC, 1.0f)));
        SM = fmaxf(SM + cap, NZ);
        SLZ = fmaxf(SLZ - cap, NZ);
        SUZ += recharge + excess;
        float PERC = fminf(SUZ, PERCp);
        SUZ -= PERC;
        float Q0 = K0 * fmaxf(SUZ - UZL, 0.0f);
        SUZ -= Q0;
        float Q1 = K1 * SUZ;
        SUZ -= Q1;
        SLZ = fmaxf(SLZ + PERC, 0.0f);
        float Q2 = K2 * SLZ;
        SLZ -= Q2;
        return Q0 + Q1 + Q2;
    };

    if (((G & 3) == 0) && (T >= 2 * TC)) {
        // ---- fast path: async LDS staging + 2-stage skewed pipeline ----
        const int rsub = lane >> 4;          // which row of the 4-row quad
        const int csub = (lane & 15) << 2;   // float col within the 64-basin row
        int gcol = g0 + csub;
        if (gcol > G - 4) gcol = G - 4;      // clamp (only ever hits invalid basins)

        const int nt = (T + TC - 1) / TC;    // 23 tiles
        const int FT = nt - 1;               // 22 full tiles; tail = T - FT*TC (13)

        // One tile = 16 rows x 64 basins x 3 arrays. Each width-16 load covers
        // 4 rows (64 lanes x 16B = 1KiB): 4 instrs/array, 12 per tile.
        auto issue_tile = [&](int k, int b) {
            const int t0 = k * TC;
#pragma unroll
            for (int q = 0; q < TC / 4; ++q) {
                int t = t0 + 4 * q + rsub;
                if (t > T - 1) t = T - 1;    // tail clamp: duplicate rows, never consumed
                const size_t off = (size_t)t * G + gcol;
                gload_lds16(precip + off, &lds[b][0][4 * q][0]);
                gload_lds16(temp   + off, &lds[b][1][4 * q][0]);
                gload_lds16(pet    + off, &lds[b][2][4 * q][0]);
            }
        };

        float* outp = out + (size_t)g;       // running pointer: +G per step

        issue_tile(0, 0);
        asm volatile("s_waitcnt vmcnt(0)" ::: "memory");
        __builtin_amdgcn_sched_barrier(0);

        // Prologue: snow(0) from row 0; preload forcings(1) from row 1.
        // Pipeline invariant at iteration t: (rt0,pe0) feed soil(t);
        // (prN,tmN,peN) = forcings(t+1); reads issued for t+2.
        float rt0, pe0, prN, tmN, peN;
        {
            const float prF = lds[0][0][0][lane];
            const float tmF = lds[0][1][0][lane];
            const float peF = lds[0][2][0][lane];
            rt0 = snow_phase(prF, tmF);
            pe0 = peF;
            prN = lds[0][0][1][lane];
            tmN = lds[0][1][1][lane];
            peN = lds[0][2][1][lane];
        }

        for (int k = 0; k < FT; ++k) {
            const int b = k & 1, nb = b ^ 1;
            issue_tile(k + 1, nb);           // 12 async loads, in flight across
            __builtin_amdgcn_sched_barrier(0);  // the whole tile's compute

#pragma unroll
            for (int j = 0; j < TC - 2; ++j) {   // t = k*TC + j, reads row j+2 of b
                const float prR = lds[b][0][j + 2][lane];
                const float tmR = lds[b][1][j + 2][lane];
                const float peR = lds[b][2][j + 2][lane];
                const float rt1 = snow_phase(prN, tmN);   // snow(t+1)
                const float pe1 = peN;
                const float q = soil_phase(rt0, pe0);     // soil(t)
                if (valid) *outp = q;
                outp += G;
                rt0 = rt1; pe0 = pe1;
                prN = prR; tmN = tmR; peN = peR;
            }

            // Counted wait: queue = [<=2 leftover stores][12 loads][14 stores].
            // vmcnt(14) retires exactly the leftovers + the 12 next-tile loads
            // (issued ~14 steps of compute ago -> zero stall), keeps this
            // tile's 14 stores outstanding.
            asm volatile("s_waitcnt vmcnt(14)" ::: "memory");
            __builtin_amdgcn_sched_barrier(0);

#pragma unroll
            for (int j = TC - 2; j < TC; ++j) {  // j=14,15: reads rows 0,1 of nb
                const float prR = lds[nb][0][j - (TC - 2)][lane];
                const float tmR = lds[nb][1][j - (TC - 2)][lane];
                const float peR = lds[nb][2][j - (TC - 2)][lane];
                const float rt1 = snow_phase(prN, tmN);
                const float pe1 = peN;
                const float q = soil_phase(rt0, pe0);
                if (valid) *outp = q;
                outp += G;
                rt0 = rt1; pe0 = pe1;
                prN = prR; tmN = tmR; peN = peR;
            }
        }

        // Tail tile: steps FT*TC .. T-1 (13 steps for T=365). Rolled loop,
        // dynamic LDS index -- small fraction of total, keep it simple.
        {
            const int b = FT & 1;
            const int TAIL = T - FT * TC;    // in [1, TC]
            for (int j = 0; j + 1 < TAIL; ++j) {
                const bool rd = (j + 2) < TAIL;
                const float prR = rd ? lds[b][0][j + 2][lane] : 0.0f;
                const float tmR = rd ? lds[b][1][j + 2][lane] : 0.0f;
                const float peR = rd ? lds[b][2][j + 2][lane] : 0.0f;
                const float rt1 = snow_phase(prN, tmN);
                const float pe1 = peN;
                const float q = soil_phase(rt0, pe0);
                if (valid) *outp = q;
                outp += G;
                rt0 = rt1; pe0 = pe1;
                prN = prR; tmN = tmR; peN = peR;
            }
            const float q = soil_phase(rt0, pe0);   // soil(T-1)
            if (valid) *outp = q;
        }
    } else {
        // ---- generic fallback (not taken for the bench shape) ----
        for (int t = 0; t < T; ++t) {
            const size_t idx = (size_t)t * G + gp;
            const float rt = snow_phase(precip[idx], temp[idx]);
            const float q = soil_phase(rt, pet[idx]);
            if (valid) out[idx] = q;
        }
    }
}

extern "C" void kernel_launch(void* const* d_in, const int* in_sizes, int n_in,
                              void* d_out, int out_size, void* d_ws, size_t ws_size,
                              hipStream_t stream) {
    const float* precip = (const float*)d_in[0];
    const float* temp   = (const float*)d_in[1];
    const float* pet    = (const float*)d_in[2];
    const float* phy    = (const float*)d_in[3];
    float* out = (float*)d_out;

    const int G = in_sizes[3] / 14;   // 50000
    const int T = in_sizes[0] / G;    // 365

    dim3 block(64);
    dim3 grid((G + 63) / 64);         // 782 blocks, 1 wave each
    hbv_kernel<<<grid, block, 0, stream>>>(precip, temp, pet, phy, out, G, T);
}

// Round 4
// 252.363 us; speedup vs baseline: 1.1866x; 1.0034x over previous
//
#include <hip/hip_runtime.h>

#define NZ 1e-5f
#define TC 16   // timesteps per staged chunk

__device__ __forceinline__ float fast_exp2(float x) {
#if __has_builtin(__builtin_amdgcn_exp2f)
    return __builtin_amdgcn_exp2f(x);   // v_exp_f32
#else
    return exp2f(x);
#endif
}

__device__ __forceinline__ float fast_log2(float x) {
#if __has_builtin(__builtin_amdgcn_logf)
    return __builtin_amdgcn_logf(x);    // v_log_f32 (base-2)
#else
    return log2f(x);
#endif
}

// Async global->LDS, 16B/lane. LDS dest is wave-uniform base + lane*16;
// global source address is per-lane.
__device__ __forceinline__ void gload_lds16(const float* src, float* dst_lds) {
    __builtin_amdgcn_global_load_lds(
        (const __attribute__((address_space(1))) void*)src,
        (__attribute__((address_space(3))) void*)dst_lds,
        16, 0, 0);
}

// R0-R3 post-mortem: 720 cy/step invariant across register-ring, async-LDS,
// and skewed-pipeline versions; NB=2 marginal chain cost ~350cy. Model: lone
// wave per SIMD pays full dependent-issue latency on a ~57-op serial chain.
// R4: producer-consumer WAVE SPLIT. The snow subsystem (SP,MW) is strictly
// feed-forward into soil (via rt=RAIN+tosoil): wave0 runs the whole snow scan
// + staging, streaming {rt,pe} chunks through an LDS FIFO; wave1 runs
// soil/routing one chunk behind. Doubles wave count (TLP: 1.5 waves/SIMD)
// AND cuts the critical wave's serial chain to soil-only (~40 ops).
__global__ __launch_bounds__(128, 1) void hbv_kernel(
    const float* __restrict__ precip,
    const float* __restrict__ temp,
    const float* __restrict__ pet,
    const float* __restrict__ phy,
    float* __restrict__ out,
    int G, int T)
{
    __shared__ float  ftile[2][3][TC][64];   // staged forcings   (24576 B)
    __shared__ float2 rtpe[2][TC][64];       // {rt, pe} FIFO     (16384 B)

    const int tid  = threadIdx.x;
    const int lane = tid & 63;
    const int wv   = tid >> 6;               // 0 = snow producer, 1 = soil consumer
    const int g0   = blockIdx.x * 64;
    const int g    = g0 + lane;
    const bool valid = (g < G);
    const int gp   = valid ? g : (G - 1);    // clamped param index

    // Parameter bounds (compile-time constants, folded)
    const float lo[14] = {1.0f, 50.0f, 0.05f, 0.01f, 0.001f, 0.2f, 0.0f,
                          0.0f, -2.5f, 0.5f, 0.0f, 0.0f, 0.3f, 0.0f};
    const float hi[14] = {6.0f, 1000.0f, 0.9f, 0.5f, 0.2f, 1.0f, 10.0f,
                          100.0f, 2.5f, 10.0f, 0.1f, 0.2f, 5.0f, 1.0f};

    const bool fastp = ((G & 3) == 0) && (T >= 2 * TC);

    if (fastp) {
        const int nt = (T + TC - 1) / TC;    // chunks (23 for T=365)

        if (wv == 0) {
            // ================= producer: staging + snow =================
            float p[14];
#pragma unroll
            for (int i = 0; i < 14; ++i)
                p[i] = lo[i] + phy[gp * 14 + i] * (hi[i] - lo[i]);
            const float TT = p[8], CFMAX = p[9], CWH = p[11];
            const float CFRX = p[10] * p[9];
            float SP = NZ, MW = NZ;

            const int rsub = lane >> 4;          // row within the 4-row quad
            const int csub = (lane & 15) << 2;   // float col within 64-basin row
            int gcol = g0 + csub;
            if (gcol > G - 4) gcol = G - 4;      // clamp (only invalid basins)

            // One tile = 16 rows x 64 basins x 3 arrays; 12 width-16 loads.
            auto issue_tile = [&](int k, int b) {
                const int t0 = k * TC;
#pragma unroll
                for (int q = 0; q < TC / 4; ++q) {
                    int t = t0 + 4 * q + rsub;
                    if (t > T - 1) t = T - 1;    // tail clamp: rows never consumed
                    const size_t off = (size_t)t * G + gcol;
                    gload_lds16(precip + off, &ftile[b][0][4 * q][0]);
                    gload_lds16(temp   + off, &ftile[b][1][4 * q][0]);
                    gload_lds16(pet    + off, &ftile[b][2][4 * q][0]);
                }
            };

            issue_tile(0, 0);

            for (int ph = 0; ph <= nt; ++ph) {
                if (ph < nt) {
                    const int b = ph & 1;
                    if (ph + 1 < nt) {
                        issue_tile(ph + 1, b ^ 1);
                        // retire exactly tile ph's 12 loads (issued a full
                        // phase ago -> ~free); keep tile ph+1's 12 in flight
                        asm volatile("s_waitcnt vmcnt(12)" ::: "memory");
                    } else {
                        asm volatile("s_waitcnt vmcnt(0)" ::: "memory");
                    }
                    __builtin_amdgcn_sched_barrier(0);
#pragma unroll
                    for (int j = 0; j < TC; ++j) {
                        const float pr = ftile[b][0][j][lane];
                        const float tm = ftile[b][1][j][lane];
                        const float pe = ftile[b][2][j][lane];
                        // --- snow subsystem, op-for-op as reference ---
                        const float RAIN = (tm >= TT) ? pr : 0.0f;
                        const float SNOW = pr - RAIN;
                        SP += SNOW;
                        float melt = fminf(fmaxf(CFMAX * (tm - TT), 0.0f), SP);
                        MW += melt;
                        SP -= melt;
                        float refr = fminf(fmaxf(CFRX * (TT - tm), 0.0f), MW);
                        SP += refr;
                        MW -= refr;
                        float tosoil = fmaxf(MW - CWH * SP, 0.0f);
                        MW -= tosoil;
                        rtpe[b][j][lane] = make_float2(RAIN + tosoil, pe);
                    }
                    // rt/pe ds_writes must be visible before the barrier
                    asm volatile("s_waitcnt lgkmcnt(0)" ::: "memory");
                    __builtin_amdgcn_sched_barrier(0);
                }
                __builtin_amdgcn_s_barrier();
                asm volatile("" ::: "memory");   // no LDS value caching across phases
            }
        } else {
            // ============ consumer: soil + routing + store ==============
            float p[14];
#pragma unroll
            for (int i = 0; i < 14; ++i)
                p[i] = lo[i] + phy[gp * 14 + i] * (hi[i] - lo[i]);
            const float BETA = p[0], FC = p[1], K0 = p[2], K1 = p[3], K2 = p[4];
            const float PERCp = p[6], UZL = p[7], BETAET = p[12], C = p[13];
            const float invFC   = 1.0f / FC;
            const float invLPFC = 1.0f / (p[5] * FC);
            float SM = NZ, SUZ = NZ, SLZ = NZ;

            // --- soil/routing, op-for-op as reference; consumes (rt, pe) ---
            auto soil_step = [&](float rt, float pe) -> float {
                float sw = fminf(fast_exp2(BETA * fast_log2(SM * invFC)), 1.0f);
                float recharge = rt * sw;
                SM += rt - recharge;
                float excess = fmaxf(SM - FC, 0.0f);
                SM -= excess;
                float ef = fminf(fast_exp2(BETAET * fast_log2(SM * invLPFC)), 1.0f);
                float ETact = fminf(SM, pe * ef);
                SM = fmaxf(SM - ETact, NZ);
                float cap = fminf(SLZ, C * SLZ * (1.0f - fminf(SM * invFC, 1.0f)));
                SM = fmaxf(SM + cap, NZ);
                SLZ = fmaxf(SLZ - cap, NZ);
                SUZ += recharge + excess;
                float PERC = fminf(SUZ, PERCp);
                SUZ -= PERC;
                float Q0 = K0 * fmaxf(SUZ - UZL, 0.0f);
                SUZ -= Q0;
                float Q1 = K1 * SUZ;
                SUZ -= Q1;
                SLZ = fmaxf(SLZ + PERC, 0.0f);
                float Q2 = K2 * SLZ;
                SLZ -= Q2;
                return Q0 + Q1 + Q2;
            };

            for (int ph = 0; ph <= nt; ++ph) {
                if (ph >= 1) {
                    const int c = ph - 1;        // chunk produced last phase
                    const int b = c & 1;
                    const int t0 = c * TC;
                    const int steps = (t0 + TC <= T) ? TC : (T - t0);
                    if (steps == TC) {
                        // 1-step register skew: read j+1 while computing j
                        float2 v = rtpe[b][0][lane];
#pragma unroll
                        for (int j = 0; j < TC; ++j) {
                            const float2 vn = (j + 1 < TC)
                                ? rtpe[b][j + 1][lane] : make_float2(0.f, 0.f);
                            const float q = soil_step(v.x, v.y);
                            if (valid) out[(size_t)(t0 + j) * G + g] = q;
                            v = vn;
                        }
                    } else {
                        for (int j = 0; j < steps; ++j) {
                            const float2 v = rtpe[b][j][lane];
                            const float q = soil_step(v.x, v.y);
                            if (valid) out[(size_t)(t0 + j) * G + g] = q;
                        }
                    }
                }
                __builtin_amdgcn_s_barrier();
                asm volatile("" ::: "memory");   // no LDS value caching across phases
            }
        }
    } else {
        // ---- generic fallback (not taken for the bench shape): wave0 only,
        // no barriers anywhere on this path ----
        if (wv == 0) {
            float p[14];
#pragma unroll
            for (int i = 0; i < 14; ++i)
                p[i] = lo[i] + phy[gp * 14 + i] * (hi[i] - lo[i]);
            const float BETA = p[0], FC = p[1], K0 = p[2], K1 = p[3], K2 = p[4];
            const float PERCp = p[6], UZL = p[7], TT = p[8], CFMAX = p[9];
            const float CWH = p[11], BETAET = p[12], C = p[13];
            const float invFC = 1.0f / FC, invLPFC = 1.0f / (p[5] * FC);
            const float CFRX = p[10] * p[9];
            float SP = NZ, MW = NZ, SM = NZ, SUZ = NZ, SLZ = NZ;
            for (int t = 0; t < T; ++t) {
                const size_t idx = (size_t)t * G + gp;
                const float pr = precip[idx], tm = temp[idx], pe = pet[idx];
                const float RAIN = (tm >= TT) ? pr : 0.0f;
                const float SNOW = pr - RAIN;
                SP += SNOW;
                float melt = fminf(fmaxf(CFMAX * (tm - TT), 0.0f), SP);
                MW += melt; SP -= melt;
                float refr = fminf(fmaxf(CFRX * (TT - tm), 0.0f), MW);
                SP += refr; MW -= refr;
                float tosoil = fmaxf(MW - CWH * SP, 0.0f);
                MW -= tosoil;
                float sw = fminf(fast_exp2(BETA * fast_log2(SM * invFC)), 1.0f);
                float rt = RAIN + tosoil;
                float recharge = rt * sw;
                SM += rt - recharge;
                float excess = fmaxf(SM - FC, 0.0f);
                SM -= excess;
                float ef = fminf(fast_exp2(BETAET * fast_log2(SM * invLPFC)), 1.0f);
                float ETact = fminf(SM, pe * ef);
                SM = fmaxf(SM - ETact, NZ);
                float cap = fminf(SLZ, C * SLZ * (1.0f - fminf(SM * invFC, 1.0f)));
                SM = fmaxf(SM + cap, NZ);
                SLZ = fmaxf(SLZ - cap, NZ);
                SUZ += recharge + excess;
                float PERC = fminf(SUZ, PERCp);
                SUZ -= PERC;
                float Q0 = K0 * fmaxf(SUZ - UZL, 0.0f);
                SUZ -= Q0;
                float Q1 = K1 * SUZ;
                SUZ -= Q1;
                SLZ = fmaxf(SLZ + PERC, 0.0f);
                float Q2 = K2 * SLZ;
                SLZ -= Q2;
                if (valid) out[idx] = Q0 + Q1 + Q2;
            }
        }
    }
}

extern "C" void kernel_launch(void* const* d_in, const int* in_sizes, int n_in,
                              void* d_out, int out_size, void* d_ws, size_t ws_size,
                              hipStream_t stream) {
    const float* precip = (const float*)d_in[0];
    const float* temp   = (const float*)d_in[1];
    const float* pet    = (const float*)d_in[2];
    const float* phy    = (const float*)d_in[3];
    float* out = (float*)d_out;

    const int G = in_sizes[3] / 14;   // 50000
    const int T = in_sizes[0] / G;    // 365

    dim3 block(128);                  // 2 waves: snow producer + soil consumer
    dim3 grid((G + 63) / 64);         // 782 blocks, 64 basins each
    hbv_kernel<<<grid, block, 0, stream>>>(precip, temp, pet, phy, out, G, T);
}